// Round 5
// baseline (494.718 us; speedup 1.0000x reference)
//
#include <hip/hip_runtime.h>
#include <hip/hip_cooperative_groups.h>
#include <cstdint>

namespace cg = cooperative_groups;

#define N_NODES 8192
#define DIN 128
#define WORDS_PER_ROW 256                        // u32 words per adjacency row
#define MASK_WORDS (N_NODES * WORDS_PER_ROW)     // 2M words = 8 MB
#define MAXDEG 128                               // Poisson(32): P(deg>128) ~ 1e-18
#define EPS 1e-8f
#define NBLK 1024
#define NTHR 256
#define ROWS_PER_BLK (N_NODES / NBLK)            // 8 rows per block

// workspace layout (bytes): [mask 8MB][dis 32KB][z16 2MB]
#define OFF_DIS (MASK_WORDS * 4)
#define OFF_Z16 (OFF_DIS + N_NODES * 4)

static __device__ __forceinline__ uint16_t f2bf(float f) {
    uint32_t u = __float_as_uint(f);
    return (uint16_t)((u + 0x7fffu + ((u >> 16) & 1u)) >> 16);   // RNE
}
static __device__ __forceinline__ float bf2f(uint32_t bits16) {
    return __uint_as_float(bits16 << 16);
}

// ---------------------------------------------------------------------------
// One cooperative dispatch, 4 phases separated by grid.sync():
//  P0: zero mask (+diagonal self-loop bits) AND z16 = bf16(x @ W^T)
//  P1: fire-and-forget atomicOr edge scatter (dedup via bitmask)
//  P2: per-wave popcount/scan of mask rows -> deg/dis + LDS neighbor list
//  P3: out[i][c] = b[c] + dis_i * sum_j dis_j * z16[j][c]
// LDS (list, deg) persists across grid.sync (cooperative co-residency).
// ---------------------------------------------------------------------------
__global__ __launch_bounds__(NTHR, 4) void gcn_fused(
        const int* __restrict__ ei, int E,
        const float* __restrict__ x, const float* __restrict__ W,
        const float* __restrict__ bias, float* __restrict__ out,
        uint32_t* __restrict__ mask, float* __restrict__ dis,
        uint16_t* __restrict__ z16) {
    cg::grid_group grid = cg::this_grid();
    const int blk = blockIdx.x;
    const int t = threadIdx.x;
    const int g = blk * NTHR + t;
    const int row0 = blk * ROWS_PER_BLK;

    __shared__ float    xlds[ROWS_PER_BLK][DIN];      // 4 KB (P0 only)
    __shared__ uint16_t slist[ROWS_PER_BLK][MAXDEG];  // 2 KB (P2 -> P3)
    __shared__ int      sdeg[ROWS_PER_BLK];

    // ---- P0a: zero mask + pre-set diagonal bits. 2 uint4 per thread.
    {
        uint4* m4 = (uint4*)mask;
#pragma unroll
        for (int q = 0; q < 2; q++) {
            uint32_t i4 = (uint32_t)g * 2 + q;
            uint32_t w0 = i4 * 4;                     // 4 words, all in one row
            uint32_t r = w0 >> 8;                     // row of these words
            uint32_t diag = (r << 8) + (r >> 5);      // word holding bit (r,r)
            uint4 v = make_uint4(0u, 0u, 0u, 0u);
            if (diag - w0 < 4u)
                ((uint32_t*)&v)[diag - w0] = 1u << (r & 31);
            m4[i4] = v;
        }
    }

    // ---- P0b: z16 = bf16(x @ W^T) for this block's 8 rows.
    // Two 128-col teams; team h owns rows h*4..h*4+3.
    {
        const int col = t & 127, half = t >> 7;
#pragma unroll
        for (int r = 0; r < 4; r++)
            xlds[half * 4 + r][col] = x[(size_t)(row0 + half * 4 + r) * DIN + col];
        __syncthreads();

        float acc[4] = {0.f, 0.f, 0.f, 0.f};
        const float* wrow = W + (size_t)col * DIN;
        for (int d = 0; d < DIN; d += 4) {
            float4 wv = *(const float4*)(wrow + d);   // L1/L2-hot 64 KB
#pragma unroll
            for (int r = 0; r < 4; r++) {
                const float* xr = &xlds[half * 4 + r][d];  // wave-uniform b128 broadcast
                acc[r] += xr[0] * wv.x + xr[1] * wv.y + xr[2] * wv.z + xr[3] * wv.w;
            }
        }
#pragma unroll
        for (int r = 0; r < 4; r++)
            z16[(size_t)(row0 + half * 4 + r) * DIN + col] = f2bf(acc[r]);
    }

    grid.sync();

    // ---- P1: scatter. 4 edges/thread, non-returning atomicOr (no stall).
#pragma unroll
    for (int k = 0; k < 4; k++) {
        int idx = g + k * (NBLK * NTHR);
        if (idx < E) {
            int src = ei[idx];
            int dst = ei[E + idx];
            atomicOr(&mask[src * WORDS_PER_ROW + (dst >> 5)], 1u << (dst & 31));
        }
    }

    grid.sync();

    // ---- P2: extract. Wave w handles rows row0 + 2w, row0 + 2w + 1.
    const int wv = t >> 6, lane = t & 63;
    for (int rr = 0; rr < 2; rr++) {
        int lr = wv * 2 + rr;
        int row = row0 + lr;
        uint4 w = ((const uint4*)(mask + (size_t)row * WORDS_PER_ROW))[lane];
        uint32_t wa[4] = {w.x, w.y, w.z, w.w};
        int c = __popc(w.x) + __popc(w.y) + __popc(w.z) + __popc(w.w);

        int sum = c;                                  // inclusive wave-64 scan
        for (int off = 1; off < 64; off <<= 1) {
            int v = __shfl_up(sum, off, 64);
            if (lane >= off) sum += v;
        }
        int excl = sum - c;
        if (lane == 63) {
            sdeg[lr] = sum;
            dis[row] = rsqrtf((float)sum + EPS);
        }
        int pos = excl, base = lane * 128;
#pragma unroll
        for (int k = 0; k < 4; k++) {
            uint32_t m = wa[k];
            while (m) {
                int b = __ffs(m) - 1;
                m &= m - 1;
                if (pos < MAXDEG) slist[lr][pos] = (uint16_t)(base + k * 32 + b);
                pos++;
            }
        }
    }

    grid.sync();

    // ---- P3: aggregate. Same wave handles the same 2 rows; list/deg in LDS.
    const uint32_t* zu = (const uint32_t*)z16;
    for (int rr = 0; rr < 2; rr++) {
        int lr = wv * 2 + rr;
        int row = row0 + lr;
        int n = min(sdeg[lr], MAXDEG);
        int j0 = (lane < n)      ? (int)slist[lr][lane]      : 0;
        int j1 = (64 + lane < n) ? (int)slist[lr][64 + lane] : 0;
        float d0 = dis[j0];
        float d1 = dis[j1];

        float a0 = 0.f, a1 = 0.f;
        for (int m = 0; m < n; m++) {
            int jj; float dd;
            if (m < 64) { jj = __shfl(j0, m, 64);      dd = __shfl(d0, m, 64); }
            else        { jj = __shfl(j1, m - 64, 64); dd = __shfl(d1, m - 64, 64); }
            uint32_t u = zu[(size_t)jj * 64 + lane];  // coalesced 256 B gather
            a0 += dd * bf2f(u & 0xffffu);
            a1 += dd * bf2f(u >> 16);
        }

        float di = dis[row];
        float2 bv = ((const float2*)bias)[lane];
        float2 o;
        o.x = bv.x + di * a0;
        o.y = bv.y + di * a1;
        ((float2*)out)[(size_t)row * 64 + lane] = o;
    }
}

// ---------------------------------------------------------------------------
extern "C" void kernel_launch(void* const* d_in, const int* in_sizes, int n_in,
                              void* d_out, int out_size, void* d_ws, size_t ws_size,
                              hipStream_t stream) {
    const float* x  = (const float*)d_in[0];
    const int*   ei = (const int*)d_in[1];
    const float* W  = (const float*)d_in[2];
    const float* b  = (const float*)d_in[3];
    float* out = (float*)d_out;

    int E = in_sizes[1] / 2;

    uint32_t* mask = (uint32_t*)d_ws;
    float*    dis  = (float*)   ((char*)d_ws + OFF_DIS);
    uint16_t* z16  = (uint16_t*)((char*)d_ws + OFF_Z16);

    void* args[] = {(void*)&ei, (void*)&E, (void*)&x, (void*)&W, (void*)&b,
                    (void*)&out, (void*)&mask, (void*)&dis, (void*)&z16};
    hipLaunchCooperativeKernel((const void*)gcn_fused, dim3(NBLK), dim3(NTHR),
                               args, 0, stream);
}

// Round 6
// 154.725 us; speedup vs baseline: 3.1974x; 3.1974x over previous
//
#include <hip/hip_runtime.h>
#include <cstdint>

#define N_NODES 8192
#define DIN 128
#define WORDS_PER_ROW 256                      // u32 words per adjacency row
#define MASK_WORDS (N_NODES * WORDS_PER_ROW)   // 2M words = 8 MB
#define MAXDEG 128                             // Poisson(32): P(deg>128) ~ 1e-18
#define EPS 1e-8f

// ws layout (bytes): [mask 8MB][deg 32KB][z16 2MB]
#define OFF_DEG (MASK_WORDS * 4)
#define OFF_Z16 (OFF_DEG + N_NODES * 4)

#define FILL_WORDS (MASK_WORDS + N_NODES)      // mask + deg, contiguous u32
#define FILL_BLKS (FILL_WORDS / 4 / 256)       // 2056 blocks, 1 uint4/thread
#define XW_BLKS (N_NODES / 32)                 // 256 blocks, 32 rows each

static __device__ __forceinline__ uint16_t f2bf(float f) {
    uint32_t u = __float_as_uint(f);
    return (uint16_t)((u + 0x7fffu + ((u >> 16) & 1u)) >> 16);   // RNE
}
static __device__ __forceinline__ float bf2f(uint32_t bits16) {
    return __uint_as_float(bits16 << 16);
}

// ---------------------------------------------------------------------------
// K1 prep: blocks [0,FILL_BLKS): zero mask with diagonal (self-loop) bits
// pre-set, and init deg[i]=1 (self). Blocks [FILL_BLKS,..): z16 = bf16(x@W^T).
// Fill is BW-bound, xw is VALU-bound -> co-resident waves overlap pipes.
// ---------------------------------------------------------------------------
__global__ __launch_bounds__(256) void gcn_prep(const float* __restrict__ x,
                                                const float* __restrict__ W,
                                                uint32_t* __restrict__ ws,   // mask|deg
                                                uint16_t* __restrict__ z16) {
    const int blk = blockIdx.x;
    if (blk < FILL_BLKS) {
        uint32_t i4 = (uint32_t)blk * 256 + threadIdx.x;   // uint4 index
        uint32_t w0 = i4 * 4;                              // 4 words, same region
        uint4 v;
        if (w0 < MASK_WORDS) {
            uint32_t r = w0 >> 8;                          // row of these words
            uint32_t diag = (r << 8) + (r >> 5);           // word with bit (r,r)
            v = make_uint4(0u, 0u, 0u, 0u);
            if (diag - w0 < 4u)
                ((uint32_t*)&v)[diag - w0] = 1u << (r & 31);
        } else {
            v = make_uint4(1u, 1u, 1u, 1u);                // deg init = 1 (self)
        }
        ((uint4*)ws)[i4] = v;
        return;
    }

    // ---- xw: 2 column-teams of 128; team h does rows row0+16h .. +16h+15
    int bb = blk - FILL_BLKS;
    int t = threadIdx.x;
    int col = t & 127;
    int half = t >> 7;
    int row0 = bb * 32 + half * 16;

    __shared__ float xlds[32][DIN];
    for (int r = 0; r < 16; r++)
        xlds[half * 16 + r][col] = x[(size_t)(row0 + r) * DIN + col];
    __syncthreads();

    float acc[16];
#pragma unroll
    for (int r = 0; r < 16; r++) acc[r] = 0.f;

    const float* wrow = W + (size_t)col * DIN;
    for (int d = 0; d < DIN; d += 4) {
        float4 wv = *(const float4*)(wrow + d);            // 64 KB, L1/L2-hot
#pragma unroll
        for (int r = 0; r < 16; r++) {
            const float* xr = &xlds[half * 16 + r][d];     // wave-uniform b128 broadcast
            acc[r] += xr[0] * wv.x + xr[1] * wv.y + xr[2] * wv.z + xr[3] * wv.w;
        }
    }
#pragma unroll
    for (int r = 0; r < 16; r++)
        z16[(size_t)(row0 + r) * DIN + col] = f2bf(acc[r]);
}

// ---------------------------------------------------------------------------
// K2 scatter: returning atomicOr detects first-setter (dedup); only the first
// setter bumps deg[src] (non-returning atomicAdd, no wave stall). 2 edges per
// thread, independent, to overlap the ~900-cyc atomic return latency.
// ---------------------------------------------------------------------------
#define SC_BLKS 512
__global__ __launch_bounds__(256) void gcn_scatter(const int* __restrict__ ei, int E,
                                                   uint32_t* __restrict__ mask,
                                                   uint32_t* __restrict__ deg) {
    int g = blockIdx.x * 256 + threadIdx.x;
    const int stride = SC_BLKS * 256;                      // 131072
#pragma unroll
    for (int k = 0; k < 2; k++) {
        int idx = g + k * stride;
        if (idx < E) {
            int src = ei[idx];
            int dst = ei[E + idx];
            uint32_t bit = 1u << (dst & 31);
            uint32_t old = atomicOr(&mask[src * WORDS_PER_ROW + (dst >> 5)], bit);
            if (!(old & bit))
                atomicAdd(&deg[src], 1u);                  // fire-and-forget
        }
    }
}

// ---------------------------------------------------------------------------
// K3 extagg: wave per row. (a) coalesced uint4 read of mask row, popcount +
// wave scan -> neighbor list straight into LDS (never hits global).
// (b) weights d_j = rsqrt(deg[j]+eps) from the L2-hot 32 KB deg table,
// broadcast via shfl; z16 gathers 256 B coalesced; out written as float2.
// ---------------------------------------------------------------------------
__global__ __launch_bounds__(256) void gcn_extagg(const uint32_t* __restrict__ mask,
                                                  const uint32_t* __restrict__ deg,
                                                  const uint16_t* __restrict__ z16,
                                                  const float* __restrict__ bias,
                                                  float* __restrict__ out) {
    __shared__ uint16_t slist[4][MAXDEG];
    const int wv = threadIdx.x >> 6, lane = threadIdx.x & 63;
    const int row = blockIdx.x * 4 + wv;

    uint4 w = ((const uint4*)(mask + (size_t)row * WORDS_PER_ROW))[lane];
    int c = __popc(w.x) + __popc(w.y) + __popc(w.z) + __popc(w.w);

    int sum = c;                                           // inclusive wave-64 scan
    for (int off = 1; off < 64; off <<= 1) {
        int v = __shfl_up(sum, off, 64);
        if (lane >= off) sum += v;
    }
    int excl = sum - c;
    int n = __shfl(sum, 63, 64);                           // true degree (incl self)

    uint32_t wa[4] = {w.x, w.y, w.z, w.w};
    int pos = excl, base = lane * 128;
#pragma unroll
    for (int k = 0; k < 4; k++) {
        uint32_t m = wa[k];
        while (m) {
            int b = __ffs(m) - 1;
            m &= m - 1;
            if (pos < MAXDEG) slist[wv][pos] = (uint16_t)(base + k * 32 + b);
            pos++;
        }
    }
    __syncthreads();                                       // belt-and-braces (4 waves)

    int nl = min(n, MAXDEG);
    int j0 = (lane < nl)      ? (int)slist[wv][lane]      : 0;
    int j1 = (64 + lane < nl) ? (int)slist[wv][64 + lane] : 0;
    float d0 = rsqrtf((float)deg[j0] + EPS);
    float d1 = rsqrtf((float)deg[j1] + EPS);

    const uint32_t* zu = (const uint32_t*)z16;
    float a0 = 0.f, a1 = 0.f;
    int n0 = min(nl, 64);
    for (int m = 0; m < n0; m++) {                         // no per-iter branch
        int jj = __shfl(j0, m, 64);
        float dd = __shfl(d0, m, 64);
        uint32_t u = zu[(size_t)jj * 64 + lane];           // coalesced 256 B gather
        a0 += dd * bf2f(u & 0xffffu);
        a1 += dd * bf2f(u >> 16);
    }
    for (int m = 64; m < nl; m++) {                        // rare (deg>64)
        int jj = __shfl(j1, m - 64, 64);
        float dd = __shfl(d1, m - 64, 64);
        uint32_t u = zu[(size_t)jj * 64 + lane];
        a0 += dd * bf2f(u & 0xffffu);
        a1 += dd * bf2f(u >> 16);
    }

    float di = rsqrtf((float)n + EPS);                     // own degree from popcount
    float2 bv = ((const float2*)bias)[lane];
    float2 o;
    o.x = bv.x + di * a0;
    o.y = bv.y + di * a1;
    ((float2*)out)[(size_t)row * 64 + lane] = o;
}

// ---------------------------------------------------------------------------
extern "C" void kernel_launch(void* const* d_in, const int* in_sizes, int n_in,
                              void* d_out, int out_size, void* d_ws, size_t ws_size,
                              hipStream_t stream) {
    const float* x  = (const float*)d_in[0];
    const int*   ei = (const int*)d_in[1];
    const float* W  = (const float*)d_in[2];
    const float* b  = (const float*)d_in[3];
    float* out = (float*)d_out;

    int E = in_sizes[1] / 2;

    uint32_t* mask = (uint32_t*)d_ws;                      // +deg contiguous
    uint32_t* deg  = (uint32_t*)((char*)d_ws + OFF_DEG);
    uint16_t* z16  = (uint16_t*)((char*)d_ws + OFF_Z16);

    gcn_prep<<<FILL_BLKS + XW_BLKS, 256, 0, stream>>>(x, W, mask, z16);
    gcn_scatter<<<SC_BLKS, 256, 0, stream>>>(ei, E, mask, deg);
    gcn_extagg<<<N_NODES / 4, 256, 0, stream>>>(mask, deg, z16, b, out);
}

// Round 8
// 135.349 us; speedup vs baseline: 3.6551x; 1.1432x over previous
//
#include <hip/hip_runtime.h>
#include <cstdint>

#define N_NODES 8192
#define DIN 128
#define WORDS_PER_ROW 256                      // u32 words per adjacency row
#define MASK_WORDS (N_NODES * WORDS_PER_ROW)   // 2M words = 8 MB
#define MAXDEG 128                             // Poisson(32): P(deg>128) ~ 1e-18
#define EPS 1e-8f
#define XW_BLKS 1024                           // 8 rows per block

// ws layout (bytes): [mask 8MB][dis 32KB][z16 2MB]
#define OFF_DIS (MASK_WORDS * 4)
#define OFF_Z16 (OFF_DIS + N_NODES * 4)

static __device__ __forceinline__ uint16_t f2bf(float f) {
    uint32_t u = __float_as_uint(f);
    return (uint16_t)((u + 0x7fffu + ((u >> 16) & 1u)) >> 16);   // RNE
}
static __device__ __forceinline__ float bf2f(uint32_t bits16) {
    return __uint_as_float(bits16 << 16);
}

// ---------------------------------------------------------------------------
// K1: zero mask with diagonal (self-loop) bits pre-set. 1 uint4/thread.
// ---------------------------------------------------------------------------
__global__ __launch_bounds__(256) void gcn_fill(uint32_t* __restrict__ mask) {
    uint32_t i4 = blockIdx.x * 256 + threadIdx.x;      // uint4 index
    uint32_t w0 = i4 * 4;                              // 4 words, same row
    uint32_t r = w0 >> 8;                              // row of these words
    uint32_t diag = (r << 8) + (r >> 5);               // word holding bit (r,r)
    uint4 v = make_uint4(0u, 0u, 0u, 0u);
    if (diag - w0 < 4u)
        ((uint32_t*)&v)[diag - w0] = 1u << (r & 31);
    ((uint4*)mask)[i4] = v;
}

// ---------------------------------------------------------------------------
// K2: blocks [0,XW_BLKS): z16 = bf16(x @ W^T), 8 rows/block.
//     W K-chunk (128 rows x 64 k = 8192 el) staged in LDS stride-65
//     ((col+k)&31 -> 2 lanes/bank = free); lane pulls its column chunk into
//     64 regs, reuses across 4 rows; x reads are wave-uniform (scalar/
//     broadcast, 1 line per instr).
//     blocks [XW_BLKS,..): FIRE-AND-FORGET atomicOr edge scatter.
// ---------------------------------------------------------------------------
__global__ __launch_bounds__(256) void gcn_main(const float* __restrict__ x,
                                                const float* __restrict__ W,
                                                uint16_t* __restrict__ z16,
                                                const int* __restrict__ ei, int E,
                                                uint32_t* __restrict__ mask) {
    __shared__ float wlds[128 * 65];                   // 33.3 KB
    const int blk = blockIdx.x;
    const int t = threadIdx.x;

    if (blk >= XW_BLKS) {                              // ---- scatter half
        int idx = (blk - XW_BLKS) * 256 + t;
        if (idx < E) {
            int src = ei[idx];
            int dst = ei[E + idx];
            atomicOr(&mask[src * WORDS_PER_ROW + (dst >> 5)], 1u << (dst & 31));
        }
        return;
    }

    // ---- xw half
    const int col = t & 127;
    const int team = t >> 7;
    const int row0 = blk * 8 + team * 4;

    float acc[4] = {0.f, 0.f, 0.f, 0.f};

#pragma unroll
    for (int c = 0; c < 2; c++) {                      // two 64-wide K chunks
        // stage W[:, c*64 .. +63]: 8192 elements = 8 iters x 256 thr x 4 el.
        // float4 global loads (coalesced); 4 scalar ds_writes each (padding
        // makes b128 LDS stores unaligned -- scalar is fine).
#pragma unroll
        for (int i = 0; i < 8; i++) {
            int e = (i * 256 + t) * 4;                 // 0..8188, 4 consecutive
            int wr = e >> 6, wk = e & 63;              // same row (wk <= 60)
            float4 wv = *(const float4*)(W + (size_t)wr * DIN + c * 64 + wk);
            float* d = &wlds[wr * 65 + wk];
            d[0] = wv.x; d[1] = wv.y; d[2] = wv.z; d[3] = wv.w;
        }
        __syncthreads();

        float w[64];                                   // my column's chunk
#pragma unroll
        for (int k = 0; k < 64; k++)
            w[k] = wlds[col * 65 + k];                 // conflict-free

#pragma unroll
        for (int r = 0; r < 4; r++) {
            const float4* xp = (const float4*)(x + (size_t)(row0 + r) * DIN + c * 64);
#pragma unroll
            for (int q = 0; q < 16; q++) {
                float4 xv = xp[q];                     // wave-uniform address
                acc[r] += w[q * 4 + 0] * xv.x + w[q * 4 + 1] * xv.y +
                          w[q * 4 + 2] * xv.z + w[q * 4 + 3] * xv.w;
            }
        }
        __syncthreads();                               // before re-staging
    }

#pragma unroll
    for (int r = 0; r < 4; r++)
        z16[(size_t)(row0 + r) * DIN + col] = f2bf(acc[r]);
}

// ---------------------------------------------------------------------------
// K3: per-row popcount -> dis[i] = rsqrt(deg + eps). Wave per row, coalesced
// uint4 reads, butterfly reduce.
// ---------------------------------------------------------------------------
__global__ __launch_bounds__(256) void gcn_degree(const uint32_t* __restrict__ mask,
                                                  float* __restrict__ dis) {
    int row  = blockIdx.x * 4 + (threadIdx.x >> 6);
    int lane = threadIdx.x & 63;
    uint4 w = ((const uint4*)(mask + (size_t)row * WORDS_PER_ROW))[lane];
    int c = __popc(w.x) + __popc(w.y) + __popc(w.z) + __popc(w.w);
    for (int off = 32; off > 0; off >>= 1)
        c += __shfl_down(c, off, 64);
    if (lane == 0)
        dis[row] = rsqrtf((float)c + EPS);
}

// ---------------------------------------------------------------------------
// K4: out[i][c] = b[c] + dis_i * sum_{j in row i} dis_j * z[j][c]
// Wave per row: mask uint4 read -> wave scan -> LDS neighbor list; dis/ids
// preloaded to regs, broadcast via shfl; z16 gathers 256 B coalesced.
// ---------------------------------------------------------------------------
__global__ __launch_bounds__(256) void gcn_extagg(const uint32_t* __restrict__ mask,
                                                  const float* __restrict__ dis,
                                                  const uint16_t* __restrict__ z16,
                                                  const float* __restrict__ bias,
                                                  float* __restrict__ out) {
    __shared__ uint16_t slist[4][MAXDEG];
    const int wv = threadIdx.x >> 6, lane = threadIdx.x & 63;
    const int row = blockIdx.x * 4 + wv;

    uint4 w = ((const uint4*)(mask + (size_t)row * WORDS_PER_ROW))[lane];
    int c = __popc(w.x) + __popc(w.y) + __popc(w.z) + __popc(w.w);

    int sum = c;                                       // inclusive wave-64 scan
    for (int off = 1; off < 64; off <<= 1) {
        int v = __shfl_up(sum, off, 64);
        if (lane >= off) sum += v;
    }
    int excl = sum - c;
    int n = __shfl(sum, 63, 64);                       // degree incl self

    uint32_t wa[4] = {w.x, w.y, w.z, w.w};
    int pos = excl, base = lane * 128;
#pragma unroll
    for (int k = 0; k < 4; k++) {
        uint32_t m = wa[k];
        while (m) {
            int b = __ffs(m) - 1;
            m &= m - 1;
            if (pos < MAXDEG) slist[wv][pos] = (uint16_t)(base + k * 32 + b);
            pos++;
        }
    }
    __syncthreads();                                   // cheap; isolates risk

    int nl = min(n, MAXDEG);
    int j0 = (lane < nl)      ? (int)slist[wv][lane]      : 0;
    int j1 = (64 + lane < nl) ? (int)slist[wv][64 + lane] : 0;
    float d0 = dis[j0];
    float d1 = dis[j1];

    const uint32_t* zu = (const uint32_t*)z16;
    float a0 = 0.f, a1 = 0.f;
    int n0 = min(nl, 64);
    for (int m = 0; m < n0; m++) {
        int jj = __shfl(j0, m, 64);
        float dd = __shfl(d0, m, 64);
        uint32_t u = zu[(size_t)jj * 64 + lane];       // coalesced 256 B gather
        a0 += dd * bf2f(u & 0xffffu);
        a1 += dd * bf2f(u >> 16);
    }
    for (int m = 64; m < nl; m++) {                    // rare (deg > 64)
        int jj = __shfl(j1, m - 64, 64);
        float dd = __shfl(d1, m - 64, 64);
        uint32_t u = zu[(size_t)jj * 64 + lane];
        a0 += dd * bf2f(u & 0xffffu);
        a1 += dd * bf2f(u >> 16);
    }

    float di = dis[row];
    float2 bv = ((const float2*)bias)[lane];
    float2 o;
    o.x = bv.x + di * a0;
    o.y = bv.y + di * a1;
    ((float2*)out)[(size_t)row * 64 + lane] = o;
}

// ---------------------------------------------------------------------------
extern "C" void kernel_launch(void* const* d_in, const int* in_sizes, int n_in,
                              void* d_out, int out_size, void* d_ws, size_t ws_size,
                              hipStream_t stream) {
    const float* x  = (const float*)d_in[0];
    const int*   ei = (const int*)d_in[1];
    const float* W  = (const float*)d_in[2];
    const float* b  = (const float*)d_in[3];
    float* out = (float*)d_out;

    int E = in_sizes[1] / 2;

    uint32_t* mask = (uint32_t*)d_ws;
    float*    dis  = (float*)   ((char*)d_ws + OFF_DIS);
    uint16_t* z16  = (uint16_t*)((char*)d_ws + OFF_Z16);

    gcn_fill<<<MASK_WORDS / 4 / 256, 256, 0, stream>>>(mask);

    int sc_blks = (E + 255) / 256;                     // 1024
    gcn_main<<<XW_BLKS + sc_blks, 256, 0, stream>>>(x, W, z16, ei, E, mask);

    gcn_degree<<<N_NODES / 4, 256, 0, stream>>>(mask, dis);

    gcn_extagg<<<N_NODES / 4, 256, 0, stream>>>(mask, dis, z16, b, out);
}

// Round 9
// 111.928 us; speedup vs baseline: 4.4200x; 1.2092x over previous
//
#include <hip/hip_runtime.h>
#include <cstdint>

#define N_NODES 8192
#define DIN 128
#define WORDS_PER_ROW 256                      // u32 words per adjacency row
#define MASK_WORDS (N_NODES * WORDS_PER_ROW)   // 2M words = 8 MB
#define MAXDEG 128                             // Poisson(32): P(deg>128) ~ 1e-18
#define EPS 1e-8f

// ws layout (bytes): [mask 8MB][dis 32KB][z16 2MB][x16 2MB][w16 32KB]
#define OFF_DIS (MASK_WORDS * 4)
#define OFF_Z16 (OFF_DIS + N_NODES * 4)
#define OFF_X16 (OFF_Z16 + N_NODES * DIN * 2)
#define OFF_W16 (OFF_X16 + N_NODES * DIN * 2)

// fill kernel block ranges
#define FILL_MASK_BLKS 2048                    // 2M words / 4 / 256
#define FILL_X_BLKS    256                     // 1M el / 16 / 256
#define FILL_W_BLKS    4                       // 16K el / 16 / 256

#define GEMM_BLKS 1024                         // 4096 wave-tiles / 4 waves

typedef __attribute__((ext_vector_type(8))) short short8;   // 8 bf16 (4 VGPRs)
typedef __attribute__((ext_vector_type(4))) float f32x4;    // 4 fp32 acc

static __device__ __forceinline__ uint32_t f2bfu(float f) {
    uint32_t u = __float_as_uint(f);
    return (u + 0x7fffu + ((u >> 16) & 1u)) >> 16;          // RNE
}
static __device__ __forceinline__ uint16_t f2bf(float f) { return (uint16_t)f2bfu(f); }
static __device__ __forceinline__ uint32_t pack2(float lo, float hi) {
    return f2bfu(lo) | (f2bfu(hi) << 16);
}
static __device__ __forceinline__ float bf2f(uint32_t bits16) {
    return __uint_as_float(bits16 << 16);
}

// convert 16 consecutive fp32 -> 16 bf16 (32 B) for flat thread id `tid`
static __device__ __forceinline__ void cvt16(const float* __restrict__ src,
                                             uint16_t* __restrict__ dst, int tid) {
    const float4* s = (const float4*)src + tid * 4;
    float4 f0 = s[0], f1 = s[1], f2 = s[2], f3 = s[3];
    uint4 o0, o1;
    o0.x = pack2(f0.x, f0.y); o0.y = pack2(f0.z, f0.w);
    o0.z = pack2(f1.x, f1.y); o0.w = pack2(f1.z, f1.w);
    o1.x = pack2(f2.x, f2.y); o1.y = pack2(f2.z, f2.w);
    o1.z = pack2(f3.x, f3.y); o1.w = pack2(f3.z, f3.w);
    ((uint4*)dst)[tid * 2]     = o0;
    ((uint4*)dst)[tid * 2 + 1] = o1;
}

// ---------------------------------------------------------------------------
// K1 fill: range A: zero mask + pre-set diagonal (self-loop) bits;
//          range B: x16 = bf16(x); range C: w16 = bf16(W).
// ---------------------------------------------------------------------------
__global__ __launch_bounds__(256) void gcn_fill(uint32_t* __restrict__ mask,
                                                const float* __restrict__ x,
                                                uint16_t* __restrict__ x16,
                                                const float* __restrict__ W,
                                                uint16_t* __restrict__ w16) {
    const int blk = blockIdx.x;
    const int t = threadIdx.x;
    if (blk < FILL_MASK_BLKS) {
        uint32_t i4 = (uint32_t)blk * 256 + t;             // uint4 index
        uint32_t w0 = i4 * 4;                              // 4 words, same row
        uint32_t r = w0 >> 8;                              // row of these words
        uint32_t diag = (r << 8) + (r >> 5);               // word with bit (r,r)
        uint4 v = make_uint4(0u, 0u, 0u, 0u);
        if (diag - w0 < 4u)
            ((uint32_t*)&v)[diag - w0] = 1u << (r & 31);
        ((uint4*)mask)[i4] = v;
    } else if (blk < FILL_MASK_BLKS + FILL_X_BLKS) {
        cvt16(x, x16, (blk - FILL_MASK_BLKS) * 256 + t);
    } else {
        cvt16(W, w16, (blk - FILL_MASK_BLKS - FILL_X_BLKS) * 256 + t);
    }
}

// ---------------------------------------------------------------------------
// K2 main: blocks [0,GEMM_BLKS): z16 = x16 @ w16^T via MFMA 16x16x32 bf16.
//   One wave per 16(m)x16(n) tile, 4 K-steps. Frags straight from global:
//   A: x16[m0+(lane&15)][32s + quad*8 ..+7] (16 B aligned contiguous)
//   B: w16[n0+(lane&15)][same]  (w16 = 32 KB, L1-resident)
//   C/D: row = quad*4 + r, col = lane&15  [verified layout, m89/m91]
// blocks [GEMM_BLKS,..): fire-and-forget atomicOr edge scatter.
// ---------------------------------------------------------------------------
__global__ __launch_bounds__(256) void gcn_main(const uint16_t* __restrict__ x16,
                                                const uint16_t* __restrict__ w16,
                                                uint16_t* __restrict__ z16,
                                                const int* __restrict__ ei, int E,
                                                uint32_t* __restrict__ mask) {
    const int blk = blockIdx.x;
    const int t = threadIdx.x;

    if (blk >= GEMM_BLKS) {                                // ---- scatter half
        int idx = (blk - GEMM_BLKS) * 256 + t;
        if (idx < E) {
            int src = ei[idx];
            int dst = ei[E + idx];
            atomicOr(&mask[src * WORDS_PER_ROW + (dst >> 5)], 1u << (dst & 31));
        }
        return;
    }

    const int lane = t & 63;
    const int tile = blk * 4 + (t >> 6);                   // 0..4095
    const int m0 = (tile >> 3) * 16;
    const int n0 = (tile & 7) * 16;
    const int l15 = lane & 15;
    const int quad = lane >> 4;
    const int kq = quad * 8;

    const uint16_t* arow = x16 + (size_t)(m0 + l15) * DIN + kq;
    const uint16_t* brow = w16 + (size_t)(n0 + l15) * DIN + kq;

    f32x4 acc = {0.f, 0.f, 0.f, 0.f};
#pragma unroll
    for (int s = 0; s < 4; s++) {
        short8 a = *(const short8*)(arow + s * 32);
        short8 b = *(const short8*)(brow + s * 32);
        acc = __builtin_amdgcn_mfma_f32_16x16x32_bf16(a, b, acc, 0, 0, 0);
    }

#pragma unroll
    for (int r = 0; r < 4; r++)
        z16[(size_t)(m0 + quad * 4 + r) * DIN + n0 + l15] = f2bf(acc[r]);
}

// ---------------------------------------------------------------------------
// K3 degree: per-row popcount -> dis[i] = rsqrt(deg+eps). Wave per row.
// ---------------------------------------------------------------------------
__global__ __launch_bounds__(256) void gcn_degree(const uint32_t* __restrict__ mask,
                                                  float* __restrict__ dis) {
    int row  = blockIdx.x * 4 + (threadIdx.x >> 6);
    int lane = threadIdx.x & 63;
    uint4 w = ((const uint4*)(mask + (size_t)row * WORDS_PER_ROW))[lane];
    int c = __popc(w.x) + __popc(w.y) + __popc(w.z) + __popc(w.w);
    for (int off = 32; off > 0; off >>= 1)
        c += __shfl_down(c, off, 64);
    if (lane == 0)
        dis[row] = rsqrtf((float)c + EPS);
}

// ---------------------------------------------------------------------------
// K4 extagg: wave per row: mask uint4 read -> wave scan -> LDS neighbor
// list; dis/ids preloaded to regs, broadcast via shfl; z16 gathers 256 B
// coalesced; float2 output.
// ---------------------------------------------------------------------------
__global__ __launch_bounds__(256) void gcn_extagg(const uint32_t* __restrict__ mask,
                                                  const float* __restrict__ dis,
                                                  const uint16_t* __restrict__ z16,
                                                  const float* __restrict__ bias,
                                                  float* __restrict__ out) {
    __shared__ uint16_t slist[4][MAXDEG];
    const int wv = threadIdx.x >> 6, lane = threadIdx.x & 63;
    const int row = blockIdx.x * 4 + wv;

    uint4 w = ((const uint4*)(mask + (size_t)row * WORDS_PER_ROW))[lane];
    int c = __popc(w.x) + __popc(w.y) + __popc(w.z) + __popc(w.w);

    int sum = c;                                           // inclusive wave scan
    for (int off = 1; off < 64; off <<= 1) {
        int v = __shfl_up(sum, off, 64);
        if (lane >= off) sum += v;
    }
    int excl = sum - c;
    int n = __shfl(sum, 63, 64);                           // degree incl self

    uint32_t wa[4] = {w.x, w.y, w.z, w.w};
    int pos = excl, base = lane * 128;
#pragma unroll
    for (int k = 0; k < 4; k++) {
        uint32_t m = wa[k];
        while (m) {
            int b = __ffs(m) - 1;
            m &= m - 1;
            if (pos < MAXDEG) slist[wv][pos] = (uint16_t)(base + k * 32 + b);
            pos++;
        }
    }
    __syncthreads();

    int nl = min(n, MAXDEG);
    int j0 = (lane < nl)      ? (int)slist[wv][lane]      : 0;
    int j1 = (64 + lane < nl) ? (int)slist[wv][64 + lane] : 0;
    float d0 = dis[j0];
    float d1 = dis[j1];

    const uint32_t* zu = (const uint32_t*)z16;
    float a0 = 0.f, a1 = 0.f;
    int n0 = min(nl, 64);
    for (int m = 0; m < n0; m++) {
        int jj = __shfl(j0, m, 64);
        float dd = __shfl(d0, m, 64);
        uint32_t u = zu[(size_t)jj * 64 + lane];           // coalesced 256 B
        a0 += dd * bf2f(u & 0xffffu);
        a1 += dd * bf2f(u >> 16);
    }
    for (int m = 64; m < nl; m++) {                        // rare (deg > 64)
        int jj = __shfl(j1, m - 64, 64);
        float dd = __shfl(d1, m - 64, 64);
        uint32_t u = zu[(size_t)jj * 64 + lane];
        a0 += dd * bf2f(u & 0xffffu);
        a1 += dd * bf2f(u >> 16);
    }

    float di = dis[row];
    float2 bv = ((const float2*)bias)[lane];
    float2 o;
    o.x = bv.x + di * a0;
    o.y = bv.y + di * a1;
    ((float2*)out)[(size_t)row * 64 + lane] = o;
}

// ---------------------------------------------------------------------------
extern "C" void kernel_launch(void* const* d_in, const int* in_sizes, int n_in,
                              void* d_out, int out_size, void* d_ws, size_t ws_size,
                              hipStream_t stream) {
    const float* x  = (const float*)d_in[0];
    const int*   ei = (const int*)d_in[1];
    const float* W  = (const float*)d_in[2];
    const float* b  = (const float*)d_in[3];
    float* out = (float*)d_out;

    int E = in_sizes[1] / 2;

    uint32_t* mask = (uint32_t*)d_ws;
    float*    dis  = (float*)   ((char*)d_ws + OFF_DIS);
    uint16_t* z16  = (uint16_t*)((char*)d_ws + OFF_Z16);
    uint16_t* x16  = (uint16_t*)((char*)d_ws + OFF_X16);
    uint16_t* w16  = (uint16_t*)((char*)d_ws + OFF_W16);

    gcn_fill<<<FILL_MASK_BLKS + FILL_X_BLKS + FILL_W_BLKS, 256, 0, stream>>>(
        mask, x, x16, W, w16);

    int sc_blks = (E + 255) / 256;                         // 1024
    gcn_main<<<GEMM_BLKS + sc_blks, 256, 0, stream>>>(x16, w16, z16, ei, E, mask);

    gcn_degree<<<N_NODES / 4, 256, 0, stream>>>(mask, dis);

    gcn_extagg<<<N_NODES / 4, 256, 0, stream>>>(mask, dis, z16, b, out);
}